// Round 7
// baseline (266.884 us; speedup 1.0000x reference)
//
#include <hip/hip_runtime.h>

// Problem constants (B, N, D fixed by the reference)
#define B_ 32
#define N_ 4096
#define D_ 256
#define K_ 2048            // max(1, int(N * (1 - 0.5)))

// Rank-kernel tiling: EPT=16 -> each ds_read_b128 feeds 64 VALU inst (10:1),
// vs 5:1 at EPT=8 (rounds 4-6). 1024 blocks = 4 waves/SIMD unchanged.
#define ISPLIT 1                    // i-chunks per batch (block covers all 4096 i)
#define JSPLIT 32                   // j-chunks per batch (128 keys each)
#define EPT 16                      // i-elements per thread (contiguous)
#define JSLICE (N_ / JSPLIT)        // 128 keys staged in LDS per block

// ---------------------------------------------------------------------------
// Kernel 1: compute the 64-bit sort key for every (b, i); zero rankBuf (u64
// stores) and meanAccum (ws is poisoned each launch).
// Key = (orderable(f32 noisy) << 32) | ~index  -> larger key == earlier in
// descending top-k order, ties broken by LOWER index (matches lax.top_k).
// Bit-identical to the round-0 (passing) kernel's key computation.
// ---------------------------------------------------------------------------
__global__ __launch_bounds__(256) void key_kernel(
    const float* __restrict__ attn, const float* __restrict__ noise,
    unsigned long long* __restrict__ keys,
    unsigned long long* __restrict__ rankBuf64,
    float* __restrict__ meanAccum) {
  const int t = blockIdx.x * 256 + threadIdx.x;   // 0 .. B*N-1
  float u = noise[t];
  float a = attn[t];
  float x = __fadd_rn(u, 1e-10f);              // u + 1e-10
  float l1 = (float)log((double)x);            // ~correctly-rounded f32 log
  float inner = __fadd_rn(-l1, 1e-10f);        // -log(u+1e-10) + 1e-10
  float g = -(float)log((double)inner);        // gumbel
  float noisy = __fadd_rn(a, __fmul_rn(0.1f, g));  // attn + 0.1*g (no FMA)
  unsigned int fb = __float_as_uint(noisy);
  fb = (fb & 0x80000000u) ? ~fb : (fb | 0x80000000u);  // orderable f32
  int i = t & (N_ - 1);
  keys[t] = ((unsigned long long)fb << 32) | (unsigned int)(~i);
  if (t < B_ * N_ / 4) rankBuf64[t] = 0ull;    // zero u16 rank buffer
  if (t < B_ * D_) meanAccum[t] = 0.0f;
}

// ---------------------------------------------------------------------------
// Kernel 2: tiled partial rank-by-count, EPT=16 variant.
// Block (jc, b): ranks ALL 4096 i-elements of batch b (16 contiguous per
// thread, register-held) against a 128-key j-slice staged in LDS.
// Inner loop: one broadcast ds_read_b128 (2 keys, 12-cyc issue) feeds
// 2 x 16 = 32 cmp+addc pairs = 64 VALU inst (~128 cyc) -> 10:1 VALU:DS
// (was 5:1 in rounds 4-6; tests the DS-chain-stall theory for rank's
// inferred ~60 us vs its 14 us VALU floor).
// Merge: 16 u16 partial ranks packed into 4 u64 atomicAdds (max per field
// 4095 -> no carry-out). 1M atomics, block-end, overlapped across blocks.
// ---------------------------------------------------------------------------
__global__ __launch_bounds__(256, 4) void rank_kernel(
    const unsigned long long* __restrict__ keys,
    unsigned long long* __restrict__ rankBuf64) {
  const int b = blockIdx.y;
  const int jc = blockIdx.x;               // 0..JSPLIT-1
  __shared__ __align__(16) unsigned long long lk[JSLICE];  // 1 KiB

  const unsigned long long* __restrict__ bk = keys + (size_t)b * N_;

  // stage the j-slice (threads 0..127, coalesced u64 loads)
  if (threadIdx.x < JSLICE) lk[threadIdx.x] = bk[jc * JSLICE + threadIdx.x];

  // this thread's EPT=16 contiguous i-keys (8 x 16B loads, 128 B per lane)
  const int ibase = threadIdx.x * EPT;
  unsigned long long ki[EPT];
  const ulonglong2* __restrict__ gi2 = (const ulonglong2*)(bk + ibase);
#pragma unroll
  for (int e2 = 0; e2 < EPT / 2; ++e2) {
    ulonglong2 v = gi2[e2];
    ki[2 * e2] = v.x;
    ki[2 * e2 + 1] = v.y;
  }
  __syncthreads();

  const ulonglong2* lk2 = (const ulonglong2*)lk;
  unsigned int rk[EPT] = {};
#pragma unroll 2
  for (int j = 0; j < JSLICE / 2; ++j) {
    ulonglong2 v = lk2[j];                 // broadcast read, conflict-free
#pragma unroll
    for (int e = 0; e < EPT; ++e) {
      rk[e] += (v.x > ki[e]);
      rk[e] += (v.y > ki[e]);
    }
  }

  // pack 16 u16 partial ranks -> 4 u64 atomic adds (little-endian fields)
  const size_t q = ((size_t)b * N_ + ibase) >> 2;   // u64 index (ibase%4==0)
#pragma unroll
  for (int p = 0; p < EPT / 4; ++p) {
    unsigned long long pk =
        (unsigned long long)rk[4 * p] |
        ((unsigned long long)rk[4 * p + 1] << 16) |
        ((unsigned long long)rk[4 * p + 2] << 32) |
        ((unsigned long long)rk[4 * p + 3] << 48);
    atomicAdd(&rankBuf64[q + p], pk);
  }
}

// ---------------------------------------------------------------------------
// Kernel 3: pruned-row mean accumulation, reading ranks directly.
// Grid (32, B) = 1024 blocks, 128 i's per block. Threads < 128 collect
// pruned indices into an LDS list; then 4 x 64-lane wave-groups gather the
// rows (1 KB coalesced each) and reduce. (Unchanged from round 6.)
// ---------------------------------------------------------------------------
__global__ __launch_bounds__(256) void mean_kernel(
    const unsigned short* __restrict__ rankBuf16, const float* __restrict__ seq,
    float* __restrict__ meanAccum) {
  const int b = blockIdx.y;
  const int ibase = blockIdx.x * 128;       // grid.x = 32
  __shared__ int plist[128];
  __shared__ int pcount;
  if (threadIdx.x == 0) pcount = 0;
  __syncthreads();
  if (threadIdx.x < 128) {
    const int i = ibase + threadIdx.x;
    const unsigned int rank = rankBuf16[(size_t)b * N_ + i];
    if (rank >= K_) {
      int slot = atomicAdd(&pcount, 1);
      plist[slot] = i;
    }
  }
  __syncthreads();
  const int cnt = pcount;

  const int dv = threadIdx.x & 63;        // float4 column 0..63
  const int sub = threadIdx.x >> 6;       // wave-group 0..3
  float4 acc = make_float4(0.f, 0.f, 0.f, 0.f);
  for (int r = sub; r < cnt; r += 4) {
    const float4* row = (const float4*)(seq + ((size_t)b * N_ + plist[r]) * D_);
    float4 v = row[dv];
    acc.x += v.x; acc.y += v.y; acc.z += v.z; acc.w += v.w;
  }

  __shared__ float4 red[4][64];
  red[sub][dv] = acc;
  __syncthreads();
  if (sub == 0) {
    float4 s0 = red[0][dv], s1 = red[1][dv], s2 = red[2][dv], s3 = red[3][dv];
    float sx = s0.x + s1.x + s2.x + s3.x;
    float sy = s0.y + s1.y + s2.y + s3.y;
    float sz = s0.z + s1.z + s2.z + s3.z;
    float sw = s0.w + s1.w + s2.w + s3.w;
    float* dst = meanAccum + b * D_ + dv * 4;
    atomicAdd(dst + 0, sx);
    atomicAdd(dst + 1, sy);
    atomicAdd(dst + 2, sz);
    atomicAdd(dst + 3, sw);
  }
}

// ---------------------------------------------------------------------------
// Kernel 4: scatter-style output, reading ranks directly.
// Grid (32, B) = 1024 blocks, 128 i's per block. Selected (rank < K) rows
// collected into an LDS list; 4 x 64-lane wave-groups copy each row:
// out[b][rank][:] = seq[b][i][:] + 0.05 * mean  (1 KB coalesced read AND
// write). Ranks are a permutation -> every out row written exactly once.
// (Unchanged from round 6.)
// ---------------------------------------------------------------------------
__global__ __launch_bounds__(256) void out_kernel(
    const unsigned short* __restrict__ rankBuf16, const float* __restrict__ seq,
    const float* __restrict__ meanAccum, float* __restrict__ out) {
  const int b = blockIdx.y;
  const int ibase = blockIdx.x * 128;       // grid.x = 32
  __shared__ int pl_i[128];
  __shared__ unsigned short pl_r[128];
  __shared__ int pcount;
  if (threadIdx.x == 0) pcount = 0;
  __syncthreads();
  if (threadIdx.x < 128) {
    const int i = ibase + threadIdx.x;
    const unsigned int rank = rankBuf16[(size_t)b * N_ + i];
    if (rank < K_) {
      int slot = atomicAdd(&pcount, 1);
      pl_i[slot] = i;
      pl_r[slot] = (unsigned short)rank;
    }
  }
  __syncthreads();
  const int cnt = pcount;

  const int dv = threadIdx.x & 63;        // float4 column 0..63
  const int sub = threadIdx.x >> 6;       // wave-group 0..3
  float4 m = ((const float4*)(meanAccum + b * D_))[dv];
  const float s = 0.05f * (1.0f / 2048.0f);  // count = 2048 (+1e-10 is sub-ulp)
  float4 mix;
  mix.x = m.x * s; mix.y = m.y * s; mix.z = m.z * s; mix.w = m.w * s;

  for (int r = sub; r < cnt; r += 4) {
    const float4* row = (const float4*)(seq + ((size_t)b * N_ + pl_i[r]) * D_);
    float4 v = row[dv];
    float4 o;
    o.x = v.x + mix.x; o.y = v.y + mix.y; o.z = v.z + mix.z; o.w = v.w + mix.w;
    ((float4*)(out + ((size_t)b * K_ + pl_r[r]) * D_))[dv] = o;
  }
}

// ---------------------------------------------------------------------------
extern "C" void kernel_launch(void* const* d_in, const int* in_sizes, int n_in,
                              void* d_out, int out_size, void* d_ws, size_t ws_size,
                              hipStream_t stream) {
  const float* seq  = (const float*)d_in[0];
  const float* attn = (const float*)d_in[1];
  const float* nois = (const float*)d_in[2];
  float* out = (float*)d_out;

  // workspace layout (1.28 MiB total)
  float* meanAccum = (float*)d_ws;                                      // 32 KiB
  unsigned long long* keys =
      (unsigned long long*)((char*)d_ws + (size_t)B_ * D_ * 4);         // 1 MiB
  unsigned long long* rankBuf64 =
      (unsigned long long*)((char*)keys + (size_t)B_ * N_ * 8);         // 256 KiB (u16[B*N])
  unsigned short* rankBuf16 = (unsigned short*)rankBuf64;

  key_kernel<<<(B_ * N_) / 256, 256, 0, stream>>>(attn, nois, keys, rankBuf64, meanAccum);
  rank_kernel<<<dim3(JSPLIT, B_), 256, 0, stream>>>(keys, rankBuf64);
  mean_kernel<<<dim3(32, B_), 256, 0, stream>>>(rankBuf16, seq, meanAccum);
  out_kernel<<<dim3(32, B_), 256, 0, stream>>>(rankBuf16, seq, meanAccum, out);
}

// Round 8
// 260.388 us; speedup vs baseline: 1.0249x; 1.0249x over previous
//
#include <hip/hip_runtime.h>

// Problem constants (B, N, D fixed by the reference)
#define B_ 32
#define N_ 4096
#define D_ 256
#define K_ 2048            // max(1, int(N * (1 - 0.5)))

// Rank-kernel tiling (r6 geometry: 1024 blocks = 4 waves/SIMD)
#define ISPLIT 2                    // i-chunks per batch (2048 elements each)
#define JSPLIT 16                   // j-chunks per batch (256 keys each)
#define EPT 8                       // i-elements per thread (contiguous)
#define JSLICE (N_ / JSPLIT)        // 256 j-keys per block
#define JCHUNK 16                   // j-keys per SGPR chunk (s_load_dwordx16 x2)

// ---------------------------------------------------------------------------
// Kernel 1: compute the 64-bit sort key for every (b, i); zero rankBuf (u64
// stores) and meanAccum (ws is poisoned each launch).
// Key = (orderable(f32 noisy) << 32) | ~index  -> larger key == earlier in
// descending top-k order, ties broken by LOWER index (matches lax.top_k).
// Bit-identical to the round-0 (passing) kernel's key computation.
// ---------------------------------------------------------------------------
__global__ __launch_bounds__(256) void key_kernel(
    const float* __restrict__ attn, const float* __restrict__ noise,
    unsigned long long* __restrict__ keys,
    unsigned long long* __restrict__ rankBuf64,
    float* __restrict__ meanAccum) {
  const int t = blockIdx.x * 256 + threadIdx.x;   // 0 .. B*N-1
  float u = noise[t];
  float a = attn[t];
  float x = __fadd_rn(u, 1e-10f);              // u + 1e-10
  float l1 = (float)log((double)x);            // ~correctly-rounded f32 log
  float inner = __fadd_rn(-l1, 1e-10f);        // -log(u+1e-10) + 1e-10
  float g = -(float)log((double)inner);        // gumbel
  float noisy = __fadd_rn(a, __fmul_rn(0.1f, g));  // attn + 0.1*g (no FMA)
  unsigned int fb = __float_as_uint(noisy);
  fb = (fb & 0x80000000u) ? ~fb : (fb | 0x80000000u);  // orderable f32
  int i = t & (N_ - 1);
  keys[t] = ((unsigned long long)fb << 32) | (unsigned int)(~i);
  if (t < B_ * N_ / 4) rankBuf64[t] = 0ull;    // zero u16 rank buffer
  if (t < B_ * D_) meanAccum[t] = 0.0f;
}

// ---------------------------------------------------------------------------
// Kernel 2: tiled partial rank-by-count — SGPR-broadcast j-keys (no LDS).
// Block (ic, jc, b): ranks 2048 i-elements (EPT=8 contiguous per thread,
// register-held) against a 256-key j-slice streamed through SGPRs in
// 16-key chunks. The j-slice address is wave-uniform, so each chunk is two
// s_load_dwordx16 (SMEM pipe, ~200 cyc latency) feeding 16 x 8 = 128
// cmp/addc pairs (~512 VALU cyc) -> latency hidden, and the compare is the
// minimal form: v_cmp_gt_u64 vcc, s[pair], v[ki] ; v_addc.
// This is the delivery-pipe A/B vs rounds 4-7 (LDS broadcast, rank ~60 us):
// r3 proved the compiler emits the scalar path for uniform key reads
// (VGPR_Count=12) and that pure compare VALU time is ~20-27 us.
// Merge unchanged: 8 u16 partial ranks packed into 2 u64 atomicAdds.
// ---------------------------------------------------------------------------
__global__ __launch_bounds__(256) void rank_kernel(
    const unsigned long long* __restrict__ keys,
    unsigned long long* __restrict__ rankBuf64) {
  const int b = blockIdx.y;
  const int ic = blockIdx.x >> 4;          // 0..ISPLIT-1
  const int jc = blockIdx.x & (JSPLIT - 1);

  const unsigned long long* __restrict__ bk = keys + (size_t)b * N_;

  // this thread's EPT contiguous i-keys; the wave covers a contiguous 4 KB
  // span via 4x global_load_dwordx4 per lane.
  const int ibase = ic * (N_ / ISPLIT) + threadIdx.x * EPT;
  unsigned long long ki[EPT];
  const ulonglong2* __restrict__ gi2 = (const ulonglong2*)(bk + ibase);
#pragma unroll
  for (int e2 = 0; e2 < EPT / 2; ++e2) {
    ulonglong2 v = gi2[e2];
    ki[2 * e2] = v.x;
    ki[2 * e2 + 1] = v.y;
  }

  // j-slice: wave-uniform base -> scalar loads, streamed in 16-key chunks
  const unsigned long long* __restrict__ js = bk + jc * JSLICE;
  unsigned int rk[EPT] = {0u, 0u, 0u, 0u, 0u, 0u, 0u, 0u};
#pragma unroll 2
  for (int c = 0; c < JSLICE / JCHUNK; ++c) {
    unsigned long long sj[JCHUNK];
#pragma unroll
    for (int q = 0; q < JCHUNK; ++q) sj[q] = js[c * JCHUNK + q];
#pragma unroll
    for (int q = 0; q < JCHUNK; ++q) {
#pragma unroll
      for (int e = 0; e < EPT; ++e) rk[e] += (sj[q] > ki[e]);
    }
  }

  // pack 8 u16 partial ranks -> 2 u64 atomic adds (little-endian field order
  // matches the u16 array layout; max per field 4095 -> no carry-out)
  unsigned long long p0 =
      (unsigned long long)rk[0] | ((unsigned long long)rk[1] << 16) |
      ((unsigned long long)rk[2] << 32) | ((unsigned long long)rk[3] << 48);
  unsigned long long p1 =
      (unsigned long long)rk[4] | ((unsigned long long)rk[5] << 16) |
      ((unsigned long long)rk[6] << 32) | ((unsigned long long)rk[7] << 48);
  const size_t q = ((size_t)b * N_ + ibase) >> 2;   // u64 index (ibase%4==0)
  atomicAdd(&rankBuf64[q], p0);
  atomicAdd(&rankBuf64[q + 1], p1);
}

// ---------------------------------------------------------------------------
// Kernel 3: pruned-row mean accumulation, reading ranks directly.
// Grid (32, B) = 1024 blocks, 128 i's per block. Threads < 128 collect
// pruned indices into an LDS list; then 4 x 64-lane wave-groups gather the
// rows (1 KB coalesced each) and reduce. (Unchanged from round 6.)
// ---------------------------------------------------------------------------
__global__ __launch_bounds__(256) void mean_kernel(
    const unsigned short* __restrict__ rankBuf16, const float* __restrict__ seq,
    float* __restrict__ meanAccum) {
  const int b = blockIdx.y;
  const int ibase = blockIdx.x * 128;       // grid.x = 32
  __shared__ int plist[128];
  __shared__ int pcount;
  if (threadIdx.x == 0) pcount = 0;
  __syncthreads();
  if (threadIdx.x < 128) {
    const int i = ibase + threadIdx.x;
    const unsigned int rank = rankBuf16[(size_t)b * N_ + i];
    if (rank >= K_) {
      int slot = atomicAdd(&pcount, 1);
      plist[slot] = i;
    }
  }
  __syncthreads();
  const int cnt = pcount;

  const int dv = threadIdx.x & 63;        // float4 column 0..63
  const int sub = threadIdx.x >> 6;       // wave-group 0..3
  float4 acc = make_float4(0.f, 0.f, 0.f, 0.f);
  for (int r = sub; r < cnt; r += 4) {
    const float4* row = (const float4*)(seq + ((size_t)b * N_ + plist[r]) * D_);
    float4 v = row[dv];
    acc.x += v.x; acc.y += v.y; acc.z += v.z; acc.w += v.w;
  }

  __shared__ float4 red[4][64];
  red[sub][dv] = acc;
  __syncthreads();
  if (sub == 0) {
    float4 s0 = red[0][dv], s1 = red[1][dv], s2 = red[2][dv], s3 = red[3][dv];
    float sx = s0.x + s1.x + s2.x + s3.x;
    float sy = s0.y + s1.y + s2.y + s3.y;
    float sz = s0.z + s1.z + s2.z + s3.z;
    float sw = s0.w + s1.w + s2.w + s3.w;
    float* dst = meanAccum + b * D_ + dv * 4;
    atomicAdd(dst + 0, sx);
    atomicAdd(dst + 1, sy);
    atomicAdd(dst + 2, sz);
    atomicAdd(dst + 3, sw);
  }
}

// ---------------------------------------------------------------------------
// Kernel 4: scatter-style output, reading ranks directly.
// Grid (32, B) = 1024 blocks, 128 i's per block. Selected (rank < K) rows
// collected into an LDS list; 4 x 64-lane wave-groups copy each row:
// out[b][rank][:] = seq[b][i][:] + 0.05 * mean  (1 KB coalesced read AND
// write). Ranks are a permutation -> every out row written exactly once.
// (Unchanged from round 6.)
// ---------------------------------------------------------------------------
__global__ __launch_bounds__(256) void out_kernel(
    const unsigned short* __restrict__ rankBuf16, const float* __restrict__ seq,
    const float* __restrict__ meanAccum, float* __restrict__ out) {
  const int b = blockIdx.y;
  const int ibase = blockIdx.x * 128;       // grid.x = 32
  __shared__ int pl_i[128];
  __shared__ unsigned short pl_r[128];
  __shared__ int pcount;
  if (threadIdx.x == 0) pcount = 0;
  __syncthreads();
  if (threadIdx.x < 128) {
    const int i = ibase + threadIdx.x;
    const unsigned int rank = rankBuf16[(size_t)b * N_ + i];
    if (rank < K_) {
      int slot = atomicAdd(&pcount, 1);
      pl_i[slot] = i;
      pl_r[slot] = (unsigned short)rank;
    }
  }
  __syncthreads();
  const int cnt = pcount;

  const int dv = threadIdx.x & 63;        // float4 column 0..63
  const int sub = threadIdx.x >> 6;       // wave-group 0..3
  float4 m = ((const float4*)(meanAccum + b * D_))[dv];
  const float s = 0.05f * (1.0f / 2048.0f);  // count = 2048 (+1e-10 is sub-ulp)
  float4 mix;
  mix.x = m.x * s; mix.y = m.y * s; mix.z = m.z * s; mix.w = m.w * s;

  for (int r = sub; r < cnt; r += 4) {
    const float4* row = (const float4*)(seq + ((size_t)b * N_ + pl_i[r]) * D_);
    float4 v = row[dv];
    float4 o;
    o.x = v.x + mix.x; o.y = v.y + mix.y; o.z = v.z + mix.z; o.w = v.w + mix.w;
    ((float4*)(out + ((size_t)b * K_ + pl_r[r]) * D_))[dv] = o;
  }
}

// ---------------------------------------------------------------------------
extern "C" void kernel_launch(void* const* d_in, const int* in_sizes, int n_in,
                              void* d_out, int out_size, void* d_ws, size_t ws_size,
                              hipStream_t stream) {
  const float* seq  = (const float*)d_in[0];
  const float* attn = (const float*)d_in[1];
  const float* nois = (const float*)d_in[2];
  float* out = (float*)d_out;

  // workspace layout (1.28 MiB total)
  float* meanAccum = (float*)d_ws;                                      // 32 KiB
  unsigned long long* keys =
      (unsigned long long*)((char*)d_ws + (size_t)B_ * D_ * 4);         // 1 MiB
  unsigned long long* rankBuf64 =
      (unsigned long long*)((char*)keys + (size_t)B_ * N_ * 8);         // 256 KiB (u16[B*N])
  unsigned short* rankBuf16 = (unsigned short*)rankBuf64;

  key_kernel<<<(B_ * N_) / 256, 256, 0, stream>>>(attn, nois, keys, rankBuf64, meanAccum);
  rank_kernel<<<dim3(ISPLIT * JSPLIT, B_), 256, 0, stream>>>(keys, rankBuf64);
  mean_kernel<<<dim3(32, B_), 256, 0, stream>>>(rankBuf16, seq, meanAccum);
  out_kernel<<<dim3(32, B_), 256, 0, stream>>>(rankBuf16, seq, meanAccum, out);
}